// Round 1
// baseline (1523.977 us; speedup 1.0000x reference)
//
#include <hip/hip_runtime.h>
#include <hip/hip_bf16.h>

// ---------------------------------------------------------------------------
// 2-layer GCN (PyG GCNConv semantics) on MI355X.
// Layer: h = x@W ; deg[i] = 1 + indeg(i); dinv = 1/sqrt(deg);
//        out = scatter_add(dst, h[src]*dinv[src]*dinv[dst]) + h*dinv^2 + b; relu
// ---------------------------------------------------------------------------

#define THREADS 256

// --- degree count ----------------------------------------------------------
__global__ void k_count_deg(const int* __restrict__ dst, int* __restrict__ degi,
                            int n_edges) {
    int e = blockIdx.x * blockDim.x + threadIdx.x;
    if (e < n_edges) atomicAdd(&degi[dst[e]], 1);
}

__global__ void k_make_dinv(const int* __restrict__ degi, float* __restrict__ dinv,
                            int n_nodes) {
    int i = blockIdx.x * blockDim.x + threadIdx.x;
    if (i < n_nodes) dinv[i] = 1.0f / sqrtf((float)(1 + degi[i]));
}

// --- dense GEMM: H[n_rows, 64] = X[n_rows, K] @ W[K, 64] -------------------
// block = 256 threads = 4 rows x 64 cols; one wave per row -> W LDS reads
// are bank-friendly (lane i -> bank i%32, 2-way free), x-row loads are
// wave-uniform (broadcast).
template <int K>
__global__ void k_gemm(const float* __restrict__ X, const float* __restrict__ W,
                       float* __restrict__ H, int n_rows) {
    __shared__ float sW[K * 64];
    for (int i = threadIdx.x; i < K * 64; i += THREADS) sW[i] = W[i];
    __syncthreads();
    int row = blockIdx.x * 4 + (threadIdx.x >> 6);
    int col = threadIdx.x & 63;
    if (row >= n_rows) return;
    const float* xr = X + (size_t)row * K;
    float acc = 0.0f;
#pragma unroll
    for (int k = 0; k < K; ++k) acc = fmaf(xr[k], sW[k * 64 + col], acc);
    H[(size_t)row * 64 + col] = acc;
}

// --- edge aggregation: agg[dst] += h[src] * dinv[src]*dinv[dst] ------------
// 16 threads per edge, each handles a float4 (64 feats total).
__global__ void k_aggregate(const float* __restrict__ H, const int* __restrict__ src,
                            const int* __restrict__ dst, const float* __restrict__ dinv,
                            float* __restrict__ agg, int n_edges) {
    int t = blockIdx.x * blockDim.x + threadIdx.x;
    int e = t >> 4;
    if (e >= n_edges) return;
    int lane = t & 15;
    int s = src[e];
    int d = dst[e];
    float c = dinv[s] * dinv[d];
    float4 v = ((const float4*)(H + (size_t)s * 64))[lane];
    float* a = agg + (size_t)d * 64 + lane * 4;
    atomicAdd(a + 0, v.x * c);
    atomicAdd(a + 1, v.y * c);
    atomicAdd(a + 2, v.z * c);
    atomicAdd(a + 3, v.w * c);
}

// --- finalize: out = relu(agg + h*dinv^2 + b) ------------------------------
__global__ void k_finalize(const float* __restrict__ agg, const float* __restrict__ H,
                           const float* __restrict__ dinv, const float* __restrict__ b,
                           float* __restrict__ out, int n_elems) {
    int t = blockIdx.x * blockDim.x + threadIdx.x;
    if (t >= n_elems) return;
    int i = t >> 6;
    int j = t & 63;
    float di = dinv[i];
    float v = agg[t] + H[t] * di * di + b[j];
    out[t] = fmaxf(v, 0.0f);
}

extern "C" void kernel_launch(void* const* d_in, const int* in_sizes, int n_in,
                              void* d_out, int out_size, void* d_ws, size_t ws_size,
                              hipStream_t stream) {
    const float* x   = (const float*)d_in[0];
    const int*   ei  = (const int*)d_in[1];   // [2, E] int32
    const float* W1  = (const float*)d_in[2];
    const float* b1  = (const float*)d_in[3];
    const float* W2  = (const float*)d_in[4];
    const float* b2  = (const float*)d_in[5];
    float* out = (float*)d_out;

    const int n_feat  = 128;
    const int hidden  = 64;
    const int n_nodes = in_sizes[0] / n_feat;     // 50000
    const int n_edges = in_sizes[1] / 2;          // 800000
    const int* src = ei;
    const int* dst = ei + n_edges;

    // workspace layout (floats), 16B aligned chunks
    const size_t n_pad = (size_t)((n_nodes + 63) & ~63);
    float* dinv = (float*)d_ws;                   // n_pad
    int*   degi = (int*)(dinv + n_pad);           // n_pad
    float* h    = (float*)(degi + n_pad);         // n_nodes*64
    float* agg  = h + (size_t)n_nodes * hidden;   // n_nodes*64

    const int n_elems = n_nodes * hidden;

    // degrees (recomputed every call; deterministic)
    hipMemsetAsync(degi, 0, n_pad * sizeof(int), stream);
    k_count_deg<<<(n_edges + THREADS - 1) / THREADS, THREADS, 0, stream>>>(dst, degi, n_edges);
    k_make_dinv<<<(n_nodes + THREADS - 1) / THREADS, THREADS, 0, stream>>>(degi, dinv, n_nodes);

    // ---- layer 1 ----
    k_gemm<128><<<(n_nodes + 3) / 4, THREADS, 0, stream>>>(x, W1, h, n_nodes);
    hipMemsetAsync(agg, 0, (size_t)n_elems * sizeof(float), stream);
    {
        size_t total = (size_t)n_edges * 16;
        k_aggregate<<<(total + THREADS - 1) / THREADS, THREADS, 0, stream>>>(
            h, src, dst, dinv, agg, n_edges);
    }
    k_finalize<<<(n_elems + THREADS - 1) / THREADS, THREADS, 0, stream>>>(
        agg, h, dinv, b1, out, n_elems);   // layer-1 output parked in d_out

    // ---- layer 2 ----
    k_gemm<64><<<(n_nodes + 3) / 4, THREADS, 0, stream>>>(out, W2, h, n_nodes);
    hipMemsetAsync(agg, 0, (size_t)n_elems * sizeof(float), stream);
    {
        size_t total = (size_t)n_edges * 16;
        k_aggregate<<<(total + THREADS - 1) / THREADS, THREADS, 0, stream>>>(
            h, src, dst, dinv, agg, n_edges);
    }
    k_finalize<<<(n_elems + THREADS - 1) / THREADS, THREADS, 0, stream>>>(
        agg, h, dinv, b2, out, n_elems);
}

// Round 2
// 410.107 us; speedup vs baseline: 3.7160x; 3.7160x over previous
//
#include <hip/hip_runtime.h>
#include <hip/hip_bf16.h>

// ---------------------------------------------------------------------------
// 2-layer GCN (PyG GCNConv semantics) on MI355X.
//   per layer: h = x@W ; out = relu( scatter_add(dst, h[src]*c) + h*dinv^2 + b )
// Round 1 -> 2: replace 51.2M float atomics/layer with CSR-gather:
//   count deg (int atomics) -> block scan -> scatter (src,coef) by dst ->
//   one wave per node gathers+accumulates in registers (epilogue fused).
// ---------------------------------------------------------------------------

#define THREADS 256
#define SCAN_T 1024

// --- degree count ----------------------------------------------------------
__global__ void k_count_deg(const int* __restrict__ dst, int* __restrict__ degi,
                            int n_edges) {
    int e = blockIdx.x * blockDim.x + threadIdx.x;
    if (e < n_edges) atomicAdd(&degi[dst[e]], 1);
}

__global__ void k_make_dinv(const int* __restrict__ degi, float* __restrict__ dinv,
                            int n_nodes) {
    int i = blockIdx.x * blockDim.x + threadIdx.x;
    if (i < n_nodes) dinv[i] = 1.0f / sqrtf((float)(1 + degi[i]));
}

// --- single-block exclusive scan of degi -> offsets (and cursor copy) ------
__global__ void k_scan(const int* __restrict__ degi, int* __restrict__ offsets,
                       int* __restrict__ cursor, int n_nodes) {
    __shared__ int partial[SCAN_T];
    int tid = threadIdx.x;
    int chunk = (n_nodes + SCAN_T - 1) / SCAN_T;
    int lo = tid * chunk;
    int hi = min(lo + chunk, n_nodes);
    int s = 0;
    for (int i = lo; i < hi; ++i) s += degi[i];
    partial[tid] = s;
    __syncthreads();
    for (int ofs = 1; ofs < SCAN_T; ofs <<= 1) {
        int v = (tid >= ofs) ? partial[tid - ofs] : 0;
        __syncthreads();
        partial[tid] += v;
        __syncthreads();
    }
    int run = (tid > 0) ? partial[tid - 1] : 0;
    for (int i = lo; i < hi; ++i) {
        offsets[i] = run;
        cursor[i] = run;
        run += degi[i];
    }
}

// --- scatter edges into dst-sorted CSR slots -------------------------------
__global__ void k_scatter(const int* __restrict__ src, const int* __restrict__ dst,
                          const float* __restrict__ dinv, int* __restrict__ cursor,
                          int* __restrict__ edge_src, float* __restrict__ edge_coef,
                          int n_edges) {
    int e = blockIdx.x * blockDim.x + threadIdx.x;
    if (e >= n_edges) return;
    int s = src[e];
    int d = dst[e];
    int pos = atomicAdd(&cursor[d], 1);
    edge_src[pos] = s;
    edge_coef[pos] = dinv[s] * dinv[d];
}

// --- dense GEMM: H[n_rows, 64] = X[n_rows, K] @ W[K, 64] -------------------
template <int K>
__global__ void k_gemm(const float* __restrict__ X, const float* __restrict__ W,
                       float* __restrict__ H, int n_rows) {
    __shared__ float sW[K * 64];
    for (int i = threadIdx.x; i < K * 64; i += THREADS) sW[i] = W[i];
    __syncthreads();
    int row = blockIdx.x * 4 + (threadIdx.x >> 6);
    int col = threadIdx.x & 63;
    if (row >= n_rows) return;
    const float* xr = X + (size_t)row * K;
    float acc = 0.0f;
#pragma unroll
    for (int k = 0; k < K; ++k) acc = fmaf(xr[k], sW[k * 64 + col], acc);
    H[(size_t)row * 64 + col] = acc;
}

// --- gather-aggregate + fused epilogue -------------------------------------
// one wave (64 lanes = 64 feats) per node:
//   out[d,:] = relu( sum_e coef[e]*H[src[e],:] + dinv[d]^2*H[d,:] + b )
__global__ void k_gather_agg(const float* __restrict__ H, const int* __restrict__ offsets,
                             const int* __restrict__ degi, const int* __restrict__ edge_src,
                             const float* __restrict__ edge_coef,
                             const float* __restrict__ dinv, const float* __restrict__ b,
                             float* __restrict__ out, int n_nodes) {
    int node = blockIdx.x * (THREADS / 64) + (threadIdx.x >> 6);
    if (node >= n_nodes) return;
    int lane = threadIdx.x & 63;
    int start = offsets[node];
    int cnt = degi[node];
    float acc = 0.0f;
    int k = 0;
    // 2-deep unroll for load-latency overlap
    for (; k + 2 <= cnt; k += 2) {
        int s0 = edge_src[start + k];
        int s1 = edge_src[start + k + 1];
        float c0 = edge_coef[start + k];
        float c1 = edge_coef[start + k + 1];
        float v0 = H[(size_t)s0 * 64 + lane];
        float v1 = H[(size_t)s1 * 64 + lane];
        acc = fmaf(v0, c0, acc);
        acc = fmaf(v1, c1, acc);
    }
    if (k < cnt) {
        int s0 = edge_src[start + k];
        acc = fmaf(H[(size_t)s0 * 64 + lane], edge_coef[start + k], acc);
    }
    float di = dinv[node];
    acc = fmaf(H[(size_t)node * 64 + lane], di * di, acc) + b[lane];
    out[(size_t)node * 64 + lane] = fmaxf(acc, 0.0f);
}

extern "C" void kernel_launch(void* const* d_in, const int* in_sizes, int n_in,
                              void* d_out, int out_size, void* d_ws, size_t ws_size,
                              hipStream_t stream) {
    const float* x  = (const float*)d_in[0];
    const int*   ei = (const int*)d_in[1];   // [2, E] int32
    const float* W1 = (const float*)d_in[2];
    const float* b1 = (const float*)d_in[3];
    const float* W2 = (const float*)d_in[4];
    const float* b2 = (const float*)d_in[5];
    float* out = (float*)d_out;

    const int n_feat  = 128;
    const int hidden  = 64;
    const int n_nodes = in_sizes[0] / n_feat;   // 50000
    const int n_edges = in_sizes[1] / 2;        // 800000
    const int* src = ei;
    const int* dst = ei + n_edges;

    // workspace layout (4B units, 16B-aligned chunks)
    const size_t n_pad = (size_t)((n_nodes + 63) & ~63);
    float* dinv     = (float*)d_ws;                     // n_pad
    int*   degi     = (int*)(dinv + n_pad);             // n_pad
    int*   offsets  = (int*)(degi + n_pad);             // n_pad
    int*   cursor   = (int*)(offsets + n_pad);          // n_pad
    int*   edge_src = (int*)(cursor + n_pad);           // n_edges
    const size_t e_pad = (size_t)((n_edges + 63) & ~63);
    float* edge_coef = (float*)(edge_src + e_pad);      // n_edges
    float* h         = (float*)(edge_coef + e_pad);     // n_nodes*64

    // ---- CSR build (once per call; reused by both layers) ----
    hipMemsetAsync(degi, 0, n_pad * sizeof(int), stream);
    k_count_deg<<<(n_edges + THREADS - 1) / THREADS, THREADS, 0, stream>>>(dst, degi, n_edges);
    k_make_dinv<<<(n_nodes + THREADS - 1) / THREADS, THREADS, 0, stream>>>(degi, dinv, n_nodes);
    k_scan<<<1, SCAN_T, 0, stream>>>(degi, offsets, cursor, n_nodes);
    k_scatter<<<(n_edges + THREADS - 1) / THREADS, THREADS, 0, stream>>>(
        src, dst, dinv, cursor, edge_src, edge_coef, n_edges);

    const int agg_blocks = (n_nodes + (THREADS / 64) - 1) / (THREADS / 64);

    // ---- layer 1 ----
    k_gemm<128><<<(n_nodes + 3) / 4, THREADS, 0, stream>>>(x, W1, h, n_nodes);
    k_gather_agg<<<agg_blocks, THREADS, 0, stream>>>(
        h, offsets, degi, edge_src, edge_coef, dinv, b1, out, n_nodes);

    // ---- layer 2 ----
    k_gemm<64><<<(n_nodes + 3) / 4, THREADS, 0, stream>>>(out, W2, h, n_nodes);
    k_gather_agg<<<agg_blocks, THREADS, 0, stream>>>(
        h, offsets, degi, edge_src, edge_coef, dinv, b2, out, n_nodes);
}

// Round 3
// 281.124 us; speedup vs baseline: 5.4210x; 1.4588x over previous
//
#include <hip/hip_runtime.h>
#include <hip/hip_bf16.h>

// ---------------------------------------------------------------------------
// 2-layer GCN (PyG GCNConv semantics) on MI355X.
//   per layer: h = x@W ; out = relu( scatter_add(dst, h[src]*c) + h*dinv^2 + b )
// R1->R2: CSR-gather instead of float atomics.
// R2->R3: single-block scan (110us, 1 CU) -> 3-phase device-wide scan (~10us);
//         gather unrolled 4-deep.
// ---------------------------------------------------------------------------

#define THREADS 256

// --- degree count ----------------------------------------------------------
__global__ void k_count_deg(const int* __restrict__ dst, int* __restrict__ degi,
                            int n_edges) {
    int e = blockIdx.x * blockDim.x + threadIdx.x;
    if (e < n_edges) atomicAdd(&degi[dst[e]], 1);
}

__global__ void k_make_dinv(const int* __restrict__ degi, float* __restrict__ dinv,
                            int n_nodes) {
    int i = blockIdx.x * blockDim.x + threadIdx.x;
    if (i < n_nodes) dinv[i] = 1.0f / sqrtf((float)(1 + degi[i]));
}

// --- 3-phase device-wide exclusive scan ------------------------------------
__global__ void k_scan_partial(const int* __restrict__ degi, int* __restrict__ block_sums,
                               int n_nodes) {
    __shared__ int red[THREADS];
    int i = blockIdx.x * THREADS + threadIdx.x;
    red[threadIdx.x] = (i < n_nodes) ? degi[i] : 0;
    __syncthreads();
    for (int ofs = THREADS >> 1; ofs > 0; ofs >>= 1) {
        if (threadIdx.x < ofs) red[threadIdx.x] += red[threadIdx.x + ofs];
        __syncthreads();
    }
    if (threadIdx.x == 0) block_sums[blockIdx.x] = red[0];
}

// single block; n_blocks <= THREADS. In-place exclusive scan of block_sums.
__global__ void k_scan_blocks(int* __restrict__ block_sums, int n_blocks) {
    __shared__ int s[THREADS];
    int tid = threadIdx.x;
    s[tid] = (tid < n_blocks) ? block_sums[tid] : 0;
    __syncthreads();
    for (int ofs = 1; ofs < THREADS; ofs <<= 1) {
        int v = (tid >= ofs) ? s[tid - ofs] : 0;
        __syncthreads();
        s[tid] += v;
        __syncthreads();
    }
    if (tid < n_blocks) block_sums[tid] = (tid > 0) ? s[tid - 1] : 0;
}

__global__ void k_scan_final(const int* __restrict__ degi, const int* __restrict__ block_sums,
                             int* __restrict__ offsets, int* __restrict__ cursor,
                             int n_nodes) {
    __shared__ int s[THREADS];
    int tid = threadIdx.x;
    int i = blockIdx.x * THREADS + tid;
    int v = (i < n_nodes) ? degi[i] : 0;
    s[tid] = v;
    __syncthreads();
    for (int ofs = 1; ofs < THREADS; ofs <<= 1) {
        int t = (tid >= ofs) ? s[tid - ofs] : 0;
        __syncthreads();
        s[tid] += t;
        __syncthreads();
    }
    int excl = s[tid] - v + block_sums[blockIdx.x];
    if (i < n_nodes) {
        offsets[i] = excl;
        cursor[i] = excl;
    }
}

// --- scatter edges into dst-sorted CSR slots -------------------------------
__global__ void k_scatter(const int* __restrict__ src, const int* __restrict__ dst,
                          const float* __restrict__ dinv, int* __restrict__ cursor,
                          int* __restrict__ edge_src, float* __restrict__ edge_coef,
                          int n_edges) {
    int e = blockIdx.x * blockDim.x + threadIdx.x;
    if (e >= n_edges) return;
    int s = src[e];
    int d = dst[e];
    int pos = atomicAdd(&cursor[d], 1);
    edge_src[pos] = s;
    edge_coef[pos] = dinv[s] * dinv[d];
}

// --- dense GEMM: H[n_rows, 64] = X[n_rows, K] @ W[K, 64] -------------------
template <int K>
__global__ void k_gemm(const float* __restrict__ X, const float* __restrict__ W,
                       float* __restrict__ H, int n_rows) {
    __shared__ float sW[K * 64];
    for (int i = threadIdx.x; i < K * 64; i += THREADS) sW[i] = W[i];
    __syncthreads();
    int row = blockIdx.x * 4 + (threadIdx.x >> 6);
    int col = threadIdx.x & 63;
    if (row >= n_rows) return;
    const float* xr = X + (size_t)row * K;
    float acc = 0.0f;
#pragma unroll
    for (int k = 0; k < K; ++k) acc = fmaf(xr[k], sW[k * 64 + col], acc);
    H[(size_t)row * 64 + col] = acc;
}

// --- gather-aggregate + fused epilogue -------------------------------------
// one wave (64 lanes = 64 feats) per node:
//   out[d,:] = relu( sum_e coef[e]*H[src[e],:] + dinv[d]^2*H[d,:] + b )
__global__ void k_gather_agg(const float* __restrict__ H, const int* __restrict__ offsets,
                             const int* __restrict__ degi, const int* __restrict__ edge_src,
                             const float* __restrict__ edge_coef,
                             const float* __restrict__ dinv, const float* __restrict__ b,
                             float* __restrict__ out, int n_nodes) {
    int node = blockIdx.x * (THREADS / 64) + (threadIdx.x >> 6);
    if (node >= n_nodes) return;
    int lane = threadIdx.x & 63;
    int start = offsets[node];
    int cnt = degi[node];
    float acc = 0.0f;
    int k = 0;
    for (; k + 4 <= cnt; k += 4) {
        int s0 = edge_src[start + k];
        int s1 = edge_src[start + k + 1];
        int s2 = edge_src[start + k + 2];
        int s3 = edge_src[start + k + 3];
        float c0 = edge_coef[start + k];
        float c1 = edge_coef[start + k + 1];
        float c2 = edge_coef[start + k + 2];
        float c3 = edge_coef[start + k + 3];
        float v0 = H[(size_t)s0 * 64 + lane];
        float v1 = H[(size_t)s1 * 64 + lane];
        float v2 = H[(size_t)s2 * 64 + lane];
        float v3 = H[(size_t)s3 * 64 + lane];
        acc = fmaf(v0, c0, acc);
        acc = fmaf(v1, c1, acc);
        acc = fmaf(v2, c2, acc);
        acc = fmaf(v3, c3, acc);
    }
    for (; k < cnt; ++k) {
        int s0 = edge_src[start + k];
        acc = fmaf(H[(size_t)s0 * 64 + lane], edge_coef[start + k], acc);
    }
    float di = dinv[node];
    acc = fmaf(H[(size_t)node * 64 + lane], di * di, acc) + b[lane];
    out[(size_t)node * 64 + lane] = fmaxf(acc, 0.0f);
}

extern "C" void kernel_launch(void* const* d_in, const int* in_sizes, int n_in,
                              void* d_out, int out_size, void* d_ws, size_t ws_size,
                              hipStream_t stream) {
    const float* x  = (const float*)d_in[0];
    const int*   ei = (const int*)d_in[1];   // [2, E] int32
    const float* W1 = (const float*)d_in[2];
    const float* b1 = (const float*)d_in[3];
    const float* W2 = (const float*)d_in[4];
    const float* b2 = (const float*)d_in[5];
    float* out = (float*)d_out;

    const int n_feat  = 128;
    const int hidden  = 64;
    const int n_nodes = in_sizes[0] / n_feat;   // 50000
    const int n_edges = in_sizes[1] / 2;        // 800000
    const int* src = ei;
    const int* dst = ei + n_edges;

    const int scan_blocks = (n_nodes + THREADS - 1) / THREADS;   // 196 (<= 256)

    // workspace layout (4B units, 16B-aligned chunks)
    const size_t n_pad = (size_t)((n_nodes + 63) & ~63);
    float* dinv       = (float*)d_ws;                    // n_pad
    int*   degi       = (int*)(dinv + n_pad);            // n_pad
    int*   offsets    = (int*)(degi + n_pad);            // n_pad
    int*   cursor     = (int*)(offsets + n_pad);         // n_pad
    int*   block_sums = (int*)(cursor + n_pad);          // 256
    int*   edge_src   = block_sums + 256;                // n_edges
    const size_t e_pad = (size_t)((n_edges + 63) & ~63);
    float* edge_coef  = (float*)(edge_src + e_pad);      // n_edges
    float* h          = (float*)(edge_coef + e_pad);     // n_nodes*64

    // ---- CSR build (once per call; reused by both layers) ----
    hipMemsetAsync(degi, 0, n_pad * sizeof(int), stream);
    k_count_deg<<<(n_edges + THREADS - 1) / THREADS, THREADS, 0, stream>>>(dst, degi, n_edges);
    k_make_dinv<<<(n_nodes + THREADS - 1) / THREADS, THREADS, 0, stream>>>(degi, dinv, n_nodes);
    k_scan_partial<<<scan_blocks, THREADS, 0, stream>>>(degi, block_sums, n_nodes);
    k_scan_blocks<<<1, THREADS, 0, stream>>>(block_sums, scan_blocks);
    k_scan_final<<<scan_blocks, THREADS, 0, stream>>>(degi, block_sums, offsets, cursor, n_nodes);
    k_scatter<<<(n_edges + THREADS - 1) / THREADS, THREADS, 0, stream>>>(
        src, dst, dinv, cursor, edge_src, edge_coef, n_edges);

    const int agg_blocks = (n_nodes + (THREADS / 64) - 1) / (THREADS / 64);

    // ---- layer 1 ----
    k_gemm<128><<<(n_nodes + 3) / 4, THREADS, 0, stream>>>(x, W1, h, n_nodes);
    k_gather_agg<<<agg_blocks, THREADS, 0, stream>>>(
        h, offsets, degi, edge_src, edge_coef, dinv, b1, out, n_nodes);

    // ---- layer 2 ----
    k_gemm<64><<<(n_nodes + 3) / 4, THREADS, 0, stream>>>(out, W2, h, n_nodes);
    k_gather_agg<<<agg_blocks, THREADS, 0, stream>>>(
        h, offsets, degi, edge_src, edge_coef, dinv, b2, out, n_nodes);
}

// Round 4
// 209.959 us; speedup vs baseline: 7.2585x; 1.3389x over previous
//
#include <hip/hip_runtime.h>
#include <hip/hip_bf16.h>

// ---------------------------------------------------------------------------
// 2-layer GCN (PyG GCNConv semantics) on MI355X.
//   per layer: h = x@W ; out = relu( gather_csr(h[src]*c) + h*dinv^2 + b )
// R1->R2: CSR-gather instead of float atomics.
// R2->R3: device-wide 3-phase scan.
// R3->R4: register-tiled GEMM (64x64 tile, 4x4 per thread, swizzled LDS);
//         edge (src,coef) packed as int2.
// ---------------------------------------------------------------------------

#define THREADS 256

// --- degree count ----------------------------------------------------------
__global__ void k_count_deg(const int* __restrict__ dst, int* __restrict__ degi,
                            int n_edges) {
    int e = blockIdx.x * blockDim.x + threadIdx.x;
    if (e < n_edges) atomicAdd(&degi[dst[e]], 1);
}

__global__ void k_make_dinv(const int* __restrict__ degi, float* __restrict__ dinv,
                            int n_nodes) {
    int i = blockIdx.x * blockDim.x + threadIdx.x;
    if (i < n_nodes) dinv[i] = 1.0f / sqrtf((float)(1 + degi[i]));
}

// --- 3-phase device-wide exclusive scan ------------------------------------
__global__ void k_scan_partial(const int* __restrict__ degi, int* __restrict__ block_sums,
                               int n_nodes) {
    __shared__ int red[THREADS];
    int i = blockIdx.x * THREADS + threadIdx.x;
    red[threadIdx.x] = (i < n_nodes) ? degi[i] : 0;
    __syncthreads();
    for (int ofs = THREADS >> 1; ofs > 0; ofs >>= 1) {
        if (threadIdx.x < ofs) red[threadIdx.x] += red[threadIdx.x + ofs];
        __syncthreads();
    }
    if (threadIdx.x == 0) block_sums[blockIdx.x] = red[0];
}

__global__ void k_scan_blocks(int* __restrict__ block_sums, int n_blocks) {
    __shared__ int s[THREADS];
    int tid = threadIdx.x;
    s[tid] = (tid < n_blocks) ? block_sums[tid] : 0;
    __syncthreads();
    for (int ofs = 1; ofs < THREADS; ofs <<= 1) {
        int v = (tid >= ofs) ? s[tid - ofs] : 0;
        __syncthreads();
        s[tid] += v;
        __syncthreads();
    }
    if (tid < n_blocks) block_sums[tid] = (tid > 0) ? s[tid - 1] : 0;
}

__global__ void k_scan_final(const int* __restrict__ degi, const int* __restrict__ block_sums,
                             int* __restrict__ offsets, int* __restrict__ cursor,
                             int n_nodes) {
    __shared__ int s[THREADS];
    int tid = threadIdx.x;
    int i = blockIdx.x * THREADS + tid;
    int v = (i < n_nodes) ? degi[i] : 0;
    s[tid] = v;
    __syncthreads();
    for (int ofs = 1; ofs < THREADS; ofs <<= 1) {
        int t = (tid >= ofs) ? s[tid - ofs] : 0;
        __syncthreads();
        s[tid] += t;
        __syncthreads();
    }
    int excl = s[tid] - v + block_sums[blockIdx.x];
    if (i < n_nodes) {
        offsets[i] = excl;
        cursor[i] = excl;
    }
}

// --- scatter edges into dst-sorted CSR slots, packed (src, coef) -----------
__global__ void k_scatter(const int* __restrict__ src, const int* __restrict__ dst,
                          const float* __restrict__ dinv, int* __restrict__ cursor,
                          int2* __restrict__ edge_pack, int n_edges) {
    int e = blockIdx.x * blockDim.x + threadIdx.x;
    if (e >= n_edges) return;
    int s = src[e];
    int d = dst[e];
    int pos = atomicAdd(&cursor[d], 1);
    float coef = dinv[s] * dinv[d];
    edge_pack[pos] = make_int2(s, __float_as_int(coef));
}

// --- register-tiled GEMM: H[n_rows,64] = X[n_rows,K] @ W[K,64] -------------
// 64x64 block tile, 256 threads, 4x4 outputs per thread.
// sX stored k-quad XOR-swizzled: phys(r, k4) = r*K + ((k4 ^ (r&7)) << 2)
//   -> staging writes and fragment reads both bank-conflict-free, no pad.
template <int K>
__global__ __launch_bounds__(256, 2)
void k_gemm(const float* __restrict__ X, const float* __restrict__ W,
            float* __restrict__ H, int n_rows) {
    constexpr int KQ = K / 4;
    constexpr int RSH = (KQ == 32) ? 5 : 4;
    __shared__ float sW[K * 64];
    __shared__ float sX[64 * K];
    const int tid = threadIdx.x;
    const int row0 = blockIdx.x * 64;

    // stage W (direct copy, coalesced float4)
#pragma unroll
    for (int it = 0; it < (K * 64 / 4) / THREADS; ++it) {
        int idx = it * THREADS + tid;
        ((float4*)sW)[idx] = ((const float4*)W)[idx];
    }
    // stage X tile, swizzled
#pragma unroll
    for (int it = 0; it < (64 * KQ) / THREADS; ++it) {
        int idx = it * THREADS + tid;
        int kq = idx & (KQ - 1);
        int r = idx >> RSH;
        float4 g = make_float4(0.f, 0.f, 0.f, 0.f);
        int grow = row0 + r;
        if (grow < n_rows) g = *(const float4*)&X[(size_t)grow * K + 4 * kq];
        *(float4*)&sX[r * K + ((kq ^ (r & 7)) << 2)] = g;
    }
    __syncthreads();

    const int tx = tid & 15;   // col group: cols 4*tx..4*tx+3
    const int ty = tid >> 4;   // row group: rows 4*ty..4*ty+3
    float acc[4][4];
#pragma unroll
    for (int i = 0; i < 4; ++i)
#pragma unroll
        for (int j = 0; j < 4; ++j) acc[i][j] = 0.f;

#pragma unroll 2
    for (int k4 = 0; k4 < KQ; ++k4) {
        float4 b0 = *(const float4*)&sW[(4 * k4 + 0) * 64 + 4 * tx];
        float4 b1 = *(const float4*)&sW[(4 * k4 + 1) * 64 + 4 * tx];
        float4 b2 = *(const float4*)&sW[(4 * k4 + 2) * 64 + 4 * tx];
        float4 b3 = *(const float4*)&sW[(4 * k4 + 3) * 64 + 4 * tx];
#pragma unroll
        for (int i = 0; i < 4; ++i) {
            int r = 4 * ty + i;
            float4 a = *(const float4*)&sX[r * K + ((k4 ^ (r & 7)) << 2)];
            acc[i][0] = fmaf(a.x, b0.x, acc[i][0]);
            acc[i][1] = fmaf(a.x, b0.y, acc[i][1]);
            acc[i][2] = fmaf(a.x, b0.z, acc[i][2]);
            acc[i][3] = fmaf(a.x, b0.w, acc[i][3]);
            acc[i][0] = fmaf(a.y, b1.x, acc[i][0]);
            acc[i][1] = fmaf(a.y, b1.y, acc[i][1]);
            acc[i][2] = fmaf(a.y, b1.z, acc[i][2]);
            acc[i][3] = fmaf(a.y, b1.w, acc[i][3]);
            acc[i][0] = fmaf(a.z, b2.x, acc[i][0]);
            acc[i][1] = fmaf(a.z, b2.y, acc[i][1]);
            acc[i][2] = fmaf(a.z, b2.z, acc[i][2]);
            acc[i][3] = fmaf(a.z, b2.w, acc[i][3]);
            acc[i][0] = fmaf(a.w, b3.x, acc[i][0]);
            acc[i][1] = fmaf(a.w, b3.y, acc[i][1]);
            acc[i][2] = fmaf(a.w, b3.z, acc[i][2]);
            acc[i][3] = fmaf(a.w, b3.w, acc[i][3]);
        }
    }

#pragma unroll
    for (int i = 0; i < 4; ++i) {
        int grow = row0 + 4 * ty + i;
        if (grow < n_rows) {
            float4 o = make_float4(acc[i][0], acc[i][1], acc[i][2], acc[i][3]);
            *(float4*)&H[(size_t)grow * 64 + 4 * tx] = o;
        }
    }
}

// --- gather-aggregate + fused epilogue -------------------------------------
// one wave (64 lanes = 64 feats) per node:
//   out[d,:] = relu( sum_e coef[e]*H[src[e],:] + dinv[d]^2*H[d,:] + b )
__global__ void k_gather_agg(const float* __restrict__ H, const int* __restrict__ offsets,
                             const int* __restrict__ degi, const int2* __restrict__ edge_pack,
                             const float* __restrict__ dinv, const float* __restrict__ b,
                             float* __restrict__ out, int n_nodes) {
    int node = blockIdx.x * (THREADS / 64) + (threadIdx.x >> 6);
    if (node >= n_nodes) return;
    int lane = threadIdx.x & 63;
    int start = offsets[node];
    int cnt = degi[node];
    float acc = 0.0f;
    int k = 0;
    for (; k + 4 <= cnt; k += 4) {
        int2 p0 = edge_pack[start + k];
        int2 p1 = edge_pack[start + k + 1];
        int2 p2 = edge_pack[start + k + 2];
        int2 p3 = edge_pack[start + k + 3];
        float v0 = H[(size_t)p0.x * 64 + lane];
        float v1 = H[(size_t)p1.x * 64 + lane];
        float v2 = H[(size_t)p2.x * 64 + lane];
        float v3 = H[(size_t)p3.x * 64 + lane];
        acc = fmaf(v0, __int_as_float(p0.y), acc);
        acc = fmaf(v1, __int_as_float(p1.y), acc);
        acc = fmaf(v2, __int_as_float(p2.y), acc);
        acc = fmaf(v3, __int_as_float(p3.y), acc);
    }
    for (; k < cnt; ++k) {
        int2 p = edge_pack[start + k];
        acc = fmaf(H[(size_t)p.x * 64 + lane], __int_as_float(p.y), acc);
    }
    float di = dinv[node];
    acc = fmaf(H[(size_t)node * 64 + lane], di * di, acc) + b[lane];
    out[(size_t)node * 64 + lane] = fmaxf(acc, 0.0f);
}

extern "C" void kernel_launch(void* const* d_in, const int* in_sizes, int n_in,
                              void* d_out, int out_size, void* d_ws, size_t ws_size,
                              hipStream_t stream) {
    const float* x  = (const float*)d_in[0];
    const int*   ei = (const int*)d_in[1];   // [2, E] int32
    const float* W1 = (const float*)d_in[2];
    const float* b1 = (const float*)d_in[3];
    const float* W2 = (const float*)d_in[4];
    const float* b2 = (const float*)d_in[5];
    float* out = (float*)d_out;

    const int n_feat  = 128;
    const int hidden  = 64;
    const int n_nodes = in_sizes[0] / n_feat;   // 50000
    const int n_edges = in_sizes[1] / 2;        // 800000
    const int* src = ei;
    const int* dst = ei + n_edges;

    const int scan_blocks = (n_nodes + THREADS - 1) / THREADS;   // 196 (<= 256)

    // workspace layout (4B units, 16B-aligned chunks)
    const size_t n_pad = (size_t)((n_nodes + 63) & ~63);
    float* dinv       = (float*)d_ws;                    // n_pad
    int*   degi       = (int*)(dinv + n_pad);            // n_pad
    int*   offsets    = (int*)(degi + n_pad);            // n_pad
    int*   cursor     = (int*)(offsets + n_pad);         // n_pad
    int*   block_sums = (int*)(cursor + n_pad);          // 256
    const size_t e_pad = (size_t)((n_edges + 63) & ~63);
    int2*  edge_pack  = (int2*)(block_sums + 256);       // e_pad int2
    float* h          = (float*)(edge_pack + e_pad);     // n_nodes*64

    // ---- CSR build (once per call; reused by both layers) ----
    hipMemsetAsync(degi, 0, n_pad * sizeof(int), stream);
    k_count_deg<<<(n_edges + THREADS - 1) / THREADS, THREADS, 0, stream>>>(dst, degi, n_edges);
    k_make_dinv<<<(n_nodes + THREADS - 1) / THREADS, THREADS, 0, stream>>>(degi, dinv, n_nodes);
    k_scan_partial<<<scan_blocks, THREADS, 0, stream>>>(degi, block_sums, n_nodes);
    k_scan_blocks<<<1, THREADS, 0, stream>>>(block_sums, scan_blocks);
    k_scan_final<<<scan_blocks, THREADS, 0, stream>>>(degi, block_sums, offsets, cursor, n_nodes);
    k_scatter<<<(n_edges + THREADS - 1) / THREADS, THREADS, 0, stream>>>(
        src, dst, dinv, cursor, edge_pack, n_edges);

    const int gemm_blocks = (n_nodes + 63) / 64;
    const int agg_blocks = (n_nodes + (THREADS / 64) - 1) / (THREADS / 64);

    // ---- layer 1 ----
    k_gemm<128><<<gemm_blocks, THREADS, 0, stream>>>(x, W1, h, n_nodes);
    k_gather_agg<<<agg_blocks, THREADS, 0, stream>>>(
        h, offsets, degi, edge_pack, dinv, b1, out, n_nodes);

    // ---- layer 2 ----
    k_gemm<64><<<gemm_blocks, THREADS, 0, stream>>>(out, W2, h, n_nodes);
    k_gather_agg<<<agg_blocks, THREADS, 0, stream>>>(
        h, offsets, degi, edge_pack, dinv, b2, out, n_nodes);
}

// Round 5
// 201.958 us; speedup vs baseline: 7.5460x; 1.0396x over previous
//
#include <hip/hip_runtime.h>
#include <hip/hip_bf16.h>

// ---------------------------------------------------------------------------
// 2-layer GCN (PyG GCNConv semantics) on MI355X.
//   out[d] = relu( dinv[d] * ( sum_e H'[src_e] + H'[d] ) + b ),  H' = dinv .* (X@W)
// R1->R2: CSR-gather instead of float atomics.
// R2->R3: device-wide 3-phase scan.
// R3->R4: register-tiled GEMM; packed edges.
// R4->R5: factor dinv out of edge coef (GEMM epilogue scales rows by dinv)
//         -> scatter writes src only (4B, halves write-amp), gather has no
//         coef stream; gather re-shaped 16 lanes x float4, 4 nodes/wave (4x MLP).
// ---------------------------------------------------------------------------

#define THREADS 256

// --- degree count ----------------------------------------------------------
__global__ void k_count_deg(const int* __restrict__ dst, int* __restrict__ degi,
                            int n_edges) {
    int e = blockIdx.x * blockDim.x + threadIdx.x;
    if (e < n_edges) atomicAdd(&degi[dst[e]], 1);
}

__global__ void k_make_dinv(const int* __restrict__ degi, float* __restrict__ dinv,
                            int n_nodes) {
    int i = blockIdx.x * blockDim.x + threadIdx.x;
    if (i < n_nodes) dinv[i] = 1.0f / sqrtf((float)(1 + degi[i]));
}

// --- 3-phase device-wide exclusive scan ------------------------------------
__global__ void k_scan_partial(const int* __restrict__ degi, int* __restrict__ block_sums,
                               int n_nodes) {
    __shared__ int red[THREADS];
    int i = blockIdx.x * THREADS + threadIdx.x;
    red[threadIdx.x] = (i < n_nodes) ? degi[i] : 0;
    __syncthreads();
    for (int ofs = THREADS >> 1; ofs > 0; ofs >>= 1) {
        if (threadIdx.x < ofs) red[threadIdx.x] += red[threadIdx.x + ofs];
        __syncthreads();
    }
    if (threadIdx.x == 0) block_sums[blockIdx.x] = red[0];
}

__global__ void k_scan_blocks(int* __restrict__ block_sums, int n_blocks) {
    __shared__ int s[THREADS];
    int tid = threadIdx.x;
    s[tid] = (tid < n_blocks) ? block_sums[tid] : 0;
    __syncthreads();
    for (int ofs = 1; ofs < THREADS; ofs <<= 1) {
        int v = (tid >= ofs) ? s[tid - ofs] : 0;
        __syncthreads();
        s[tid] += v;
        __syncthreads();
    }
    if (tid < n_blocks) block_sums[tid] = (tid > 0) ? s[tid - 1] : 0;
}

__global__ void k_scan_final(const int* __restrict__ degi, const int* __restrict__ block_sums,
                             int* __restrict__ offsets, int* __restrict__ cursor,
                             int n_nodes) {
    __shared__ int s[THREADS];
    int tid = threadIdx.x;
    int i = blockIdx.x * THREADS + tid;
    int v = (i < n_nodes) ? degi[i] : 0;
    s[tid] = v;
    __syncthreads();
    for (int ofs = 1; ofs < THREADS; ofs <<= 1) {
        int t = (tid >= ofs) ? s[tid - ofs] : 0;
        __syncthreads();
        s[tid] += t;
        __syncthreads();
    }
    int excl = s[tid] - v + block_sums[blockIdx.x];
    if (i < n_nodes) {
        offsets[i] = excl;
        cursor[i] = excl;
    }
}

// --- scatter edges into dst-sorted CSR slots (src index only) --------------
__global__ void k_scatter(const int* __restrict__ src, const int* __restrict__ dst,
                          int* __restrict__ cursor, int* __restrict__ edge_src,
                          int n_edges) {
    int e = blockIdx.x * blockDim.x + threadIdx.x;
    if (e >= n_edges) return;
    int d = dst[e];
    int pos = atomicAdd(&cursor[d], 1);
    edge_src[pos] = src[e];
}

// --- register-tiled GEMM: H'[r,:] = dinv[r] * (X[r,:K] @ W[K,64]) ----------
// 64x64 block tile, 256 threads, 4x4 outputs per thread.
// sX stored k-quad XOR-swizzled: phys(r, k4) = r*K + ((k4 ^ (r&7)) << 2)
template <int K>
__global__ __launch_bounds__(256, 2)
void k_gemm(const float* __restrict__ X, const float* __restrict__ W,
            const float* __restrict__ dinv, float* __restrict__ H, int n_rows) {
    constexpr int KQ = K / 4;
    constexpr int RSH = (KQ == 32) ? 5 : 4;
    __shared__ float sW[K * 64];
    __shared__ float sX[64 * K];
    const int tid = threadIdx.x;
    const int row0 = blockIdx.x * 64;

    // stage W (direct copy, coalesced float4)
#pragma unroll
    for (int it = 0; it < (K * 64 / 4) / THREADS; ++it) {
        int idx = it * THREADS + tid;
        ((float4*)sW)[idx] = ((const float4*)W)[idx];
    }
    // stage X tile, swizzled
#pragma unroll
    for (int it = 0; it < (64 * KQ) / THREADS; ++it) {
        int idx = it * THREADS + tid;
        int kq = idx & (KQ - 1);
        int r = idx >> RSH;
        float4 g = make_float4(0.f, 0.f, 0.f, 0.f);
        int grow = row0 + r;
        if (grow < n_rows) g = *(const float4*)&X[(size_t)grow * K + 4 * kq];
        *(float4*)&sX[r * K + ((kq ^ (r & 7)) << 2)] = g;
    }
    __syncthreads();

    const int tx = tid & 15;   // col group: cols 4*tx..4*tx+3
    const int ty = tid >> 4;   // row group: rows 4*ty..4*ty+3
    float acc[4][4];
#pragma unroll
    for (int i = 0; i < 4; ++i)
#pragma unroll
        for (int j = 0; j < 4; ++j) acc[i][j] = 0.f;

#pragma unroll 2
    for (int k4 = 0; k4 < KQ; ++k4) {
        float4 b0 = *(const float4*)&sW[(4 * k4 + 0) * 64 + 4 * tx];
        float4 b1 = *(const float4*)&sW[(4 * k4 + 1) * 64 + 4 * tx];
        float4 b2 = *(const float4*)&sW[(4 * k4 + 2) * 64 + 4 * tx];
        float4 b3 = *(const float4*)&sW[(4 * k4 + 3) * 64 + 4 * tx];
#pragma unroll
        for (int i = 0; i < 4; ++i) {
            int r = 4 * ty + i;
            float4 a = *(const float4*)&sX[r * K + ((k4 ^ (r & 7)) << 2)];
            acc[i][0] = fmaf(a.x, b0.x, acc[i][0]);
            acc[i][1] = fmaf(a.x, b0.y, acc[i][1]);
            acc[i][2] = fmaf(a.x, b0.z, acc[i][2]);
            acc[i][3] = fmaf(a.x, b0.w, acc[i][3]);
            acc[i][0] = fmaf(a.y, b1.x, acc[i][0]);
            acc[i][1] = fmaf(a.y, b1.y, acc[i][1]);
            acc[i][2] = fmaf(a.y, b1.z, acc[i][2]);
            acc[i][3] = fmaf(a.y, b1.w, acc[i][3]);
            acc[i][0] = fmaf(a.z, b2.x, acc[i][0]);
            acc[i][1] = fmaf(a.z, b2.y, acc[i][1]);
            acc[i][2] = fmaf(a.z, b2.z, acc[i][2]);
            acc[i][3] = fmaf(a.z, b2.w, acc[i][3]);
            acc[i][0] = fmaf(a.w, b3.x, acc[i][0]);
            acc[i][1] = fmaf(a.w, b3.y, acc[i][1]);
            acc[i][2] = fmaf(a.w, b3.z, acc[i][2]);
            acc[i][3] = fmaf(a.w, b3.w, acc[i][3]);
        }
    }

#pragma unroll
    for (int i = 0; i < 4; ++i) {
        int grow = row0 + 4 * ty + i;
        if (grow < n_rows) {
            float dv = dinv[grow];
            float4 o = make_float4(acc[i][0] * dv, acc[i][1] * dv,
                                   acc[i][2] * dv, acc[i][3] * dv);
            *(float4*)&H[(size_t)grow * 64 + 4 * tx] = o;
        }
    }
}

// --- gather-aggregate + fused epilogue -------------------------------------
// 16 lanes x float4 per node, 4 nodes per wave (4x memory-level parallelism):
//   out[d,:] = relu( dinv[d] * ( sum_e H'[src_e,:] + H'[d,:] ) + b )
__global__ void k_gather_agg(const float* __restrict__ Hp, const int* __restrict__ offsets,
                             const int* __restrict__ degi, const int* __restrict__ edge_src,
                             const float* __restrict__ dinv, const float* __restrict__ b,
                             float* __restrict__ out, int n_nodes) {
    int node = blockIdx.x * (THREADS / 16) + (threadIdx.x >> 4);
    if (node >= n_nodes) return;
    int l = threadIdx.x & 15;            // float4 slot: feats 4l..4l+3
    int start = offsets[node];
    int cnt = degi[node];

    // self term
    float4 acc = ((const float4*)(Hp + (size_t)node * 64))[l];

    int k = 0;
    for (; k + 4 <= cnt; k += 4) {
        int s0 = edge_src[start + k];
        int s1 = edge_src[start + k + 1];
        int s2 = edge_src[start + k + 2];
        int s3 = edge_src[start + k + 3];
        float4 v0 = ((const float4*)(Hp + (size_t)s0 * 64))[l];
        float4 v1 = ((const float4*)(Hp + (size_t)s1 * 64))[l];
        float4 v2 = ((const float4*)(Hp + (size_t)s2 * 64))[l];
        float4 v3 = ((const float4*)(Hp + (size_t)s3 * 64))[l];
        acc.x += v0.x + v1.x + v2.x + v3.x;
        acc.y += v0.y + v1.y + v2.y + v3.y;
        acc.z += v0.z + v1.z + v2.z + v3.z;
        acc.w += v0.w + v1.w + v2.w + v3.w;
    }
    for (; k < cnt; ++k) {
        int s0 = edge_src[start + k];
        float4 v0 = ((const float4*)(Hp + (size_t)s0 * 64))[l];
        acc.x += v0.x;
        acc.y += v0.y;
        acc.z += v0.z;
        acc.w += v0.w;
    }

    float dv = dinv[node];
    float4 bb = ((const float4*)b)[l];
    float4 o;
    o.x = fmaxf(fmaf(acc.x, dv, bb.x), 0.0f);
    o.y = fmaxf(fmaf(acc.y, dv, bb.y), 0.0f);
    o.z = fmaxf(fmaf(acc.z, dv, bb.z), 0.0f);
    o.w = fmaxf(fmaf(acc.w, dv, bb.w), 0.0f);
    ((float4*)(out + (size_t)node * 64))[l] = o;
}

extern "C" void kernel_launch(void* const* d_in, const int* in_sizes, int n_in,
                              void* d_out, int out_size, void* d_ws, size_t ws_size,
                              hipStream_t stream) {
    const float* x  = (const float*)d_in[0];
    const int*   ei = (const int*)d_in[1];   // [2, E] int32
    const float* W1 = (const float*)d_in[2];
    const float* b1 = (const float*)d_in[3];
    const float* W2 = (const float*)d_in[4];
    const float* b2 = (const float*)d_in[5];
    float* out = (float*)d_out;

    const int n_feat  = 128;
    const int hidden  = 64;
    const int n_nodes = in_sizes[0] / n_feat;   // 50000
    const int n_edges = in_sizes[1] / 2;        // 800000
    const int* src = ei;
    const int* dst = ei + n_edges;

    const int scan_blocks = (n_nodes + THREADS - 1) / THREADS;   // 196 (<= 256)

    // workspace layout (4B units, 16B-aligned chunks)
    const size_t n_pad = (size_t)((n_nodes + 63) & ~63);
    float* dinv       = (float*)d_ws;                    // n_pad
    int*   degi       = (int*)(dinv + n_pad);            // n_pad
    int*   offsets    = (int*)(degi + n_pad);            // n_pad
    int*   cursor     = (int*)(offsets + n_pad);         // n_pad
    int*   block_sums = (int*)(cursor + n_pad);          // 256
    int*   edge_src   = block_sums + 256;                // e_pad
    const size_t e_pad = (size_t)((n_edges + 63) & ~63);
    float* h          = (float*)(edge_src + e_pad);      // n_nodes*64

    // ---- CSR build (once per call; reused by both layers) ----
    hipMemsetAsync(degi, 0, n_pad * sizeof(int), stream);
    k_count_deg<<<(n_edges + THREADS - 1) / THREADS, THREADS, 0, stream>>>(dst, degi, n_edges);
    k_make_dinv<<<(n_nodes + THREADS - 1) / THREADS, THREADS, 0, stream>>>(degi, dinv, n_nodes);
    k_scan_partial<<<scan_blocks, THREADS, 0, stream>>>(degi, block_sums, n_nodes);
    k_scan_blocks<<<1, THREADS, 0, stream>>>(block_sums, scan_blocks);
    k_scan_final<<<scan_blocks, THREADS, 0, stream>>>(degi, block_sums, offsets, cursor, n_nodes);
    k_scatter<<<(n_edges + THREADS - 1) / THREADS, THREADS, 0, stream>>>(
        src, dst, cursor, edge_src, n_edges);

    const int gemm_blocks = (n_nodes + 63) / 64;
    const int agg_blocks = (n_nodes + (THREADS / 16) - 1) / (THREADS / 16);

    // ---- layer 1 ----
    k_gemm<128><<<gemm_blocks, THREADS, 0, stream>>>(x, W1, dinv, h, n_nodes);
    k_gather_agg<<<agg_blocks, THREADS, 0, stream>>>(
        h, offsets, degi, edge_src, dinv, b1, out, n_nodes);

    // ---- layer 2 ----
    k_gemm<64><<<gemm_blocks, THREADS, 0, stream>>>(out, W2, dinv, h, n_nodes);
    k_gather_agg<<<agg_blocks, THREADS, 0, stream>>>(
        h, offsets, degi, edge_src, dinv, b2, out, n_nodes);
}